// Round 11
// baseline (34.311 us; speedup 1.0000x reference)
//
#include <hip/hip_runtime.h>

// Problem constants
#define NBATCH 8
#define HH 512
#define WW 512
#define NPIX (HH * WW)                 // 262144
#define IMG_ELEMS (NBATCH * 3 * NPIX)  // 6291456 floats per stitched output
#define OFF_ALBEDO 0
#define OFF_NORMAL ((size_t)IMG_ELEMS)
#define OFF_SHADING ((size_t)(2 * IMG_ELEMS))
#define OFF_LIGHT ((size_t)(3 * IMG_ELEMS))
#define N_LIGHT (NBATCH * 27 * 49)     // 10584
#define OFF_LOSS (OFF_LIGHT + N_LIGHT)
#define NBAND 128                      // 512 rows / 4-row bands
#define NBLK (NBATCH * NBAND)          // 1024 blocks (proven optimal count)
// P table: [n][band][tj(8)][c(8, padded)] = 8*128*8*8 floats = 256 KB in d_ws.
// Every slot written every call by exactly one block -> no zeroing, no atomics.
//
// R11 hypothesis: per-wave-instruction burst length. The 6.8 TB/s fill writes
// 1 KB contiguous per wave; R6's tiling gave 4 x 256B segments at 2KB stride
// per wave instruction. This layout makes EVERY load/store instruction
// 64 lanes x 16B = 1 KB fully contiguous (one row, 256 consecutive columns).

typedef float f32x4 __attribute__((ext_vector_type(4)));

__device__ __forceinline__ float fast_tanh(float x) {
    // tanh(x) = 1 - 2/(exp(2x)+1); saturates correctly at +/-inf of exp
    float e = __expf(2.0f * x);
    return 1.0f - 2.0f / (e + 1.0f);
}

// One block = 256 threads = one 4-row x 512-col band; 8 px/thread as two dense
// 4-px chunks at rows y and y+2. Wave w covers ONE row, 256 consecutive cols:
// every load/store instruction is 1 KB contiguous.
// grid = N * 128(band) = 1024 blocks = 4096 waves, 16 waves/CU.
__global__ __launch_bounds__(256) void fused_heads_kernel(
    const float* __restrict__ inT, const float* __restrict__ inN,
    const float* __restrict__ Wa, const float* __restrict__ ba,
    const float* __restrict__ Wn, const float* __restrict__ bn,
    const float* __restrict__ Ws, const float* __restrict__ bs,
    float* __restrict__ out, float* __restrict__ P) {
    int bid = blockIdx.x;
    int n = bid >> 7;           // / 128
    int band = bid & 127;

    int t = threadIdx.x;
    int half = t >> 7;          // 0..1: row within pair
    int cidx = t & 127;         // 0..127: column/4
    int x = cidx * 4;
    int y0 = band * 4 + half;   // chunk A row; chunk B at y0+2

    // 12 independent fully-dense f32x4 loads; each wave instruction = 1 KB contiguous
    f32x4 fa[6], fb[6];
    size_t base0 = ((size_t)(n * 3) * HH + y0) * WW + x;
    size_t base1 = base0 + (size_t)2 * WW;
#pragma unroll
    for (int c = 0; c < 3; ++c) {
        fa[c]     = *reinterpret_cast<const f32x4*>(inT + base0 + (size_t)c * NPIX);
        fb[c]     = *reinterpret_cast<const f32x4*>(inT + base1 + (size_t)c * NPIX);
        fa[c + 3] = *reinterpret_cast<const f32x4*>(inN + base0 + (size_t)c * NPIX);
        fb[c + 3] = *reinterpret_cast<const f32x4*>(inN + base1 + (size_t)c * NPIX);
    }

    // Three heads: out[n,o,y,x] = tanh(W[o,:].feat + b[o])
    // (stitch weights are separable and sum to 1 at every pixel -> stitch == identity;
    //  overlap_loss is identically zero since overlapping patches see the same pixels)
#pragma unroll
    for (int h = 0; h < 3; ++h) {
        const float* W = (h == 0) ? Wa : (h == 1) ? Wn : Ws;
        const float* b = (h == 0) ? ba : (h == 1) ? bn : bs;
        float* o_ptr = out + ((h == 0) ? OFF_ALBEDO : (h == 1) ? OFF_NORMAL : OFF_SHADING);
#pragma unroll
        for (int o = 0; o < 3; ++o) {
            float bv = b[o];
            f32x4 A = {bv, bv, bv, bv};
            f32x4 B = {bv, bv, bv, bv};
#pragma unroll
            for (int c = 0; c < 6; ++c) {
                float w = W[o * 6 + c];
                A.x = fmaf(w, fa[c].x, A.x);
                A.y = fmaf(w, fa[c].y, A.y);
                A.z = fmaf(w, fa[c].z, A.z);
                A.w = fmaf(w, fa[c].w, A.w);
                B.x = fmaf(w, fb[c].x, B.x);
                B.y = fmaf(w, fb[c].y, B.y);
                B.z = fmaf(w, fb[c].z, B.z);
                B.w = fmaf(w, fb[c].w, B.w);
            }
            f32x4 rA = {fast_tanh(A.x), fast_tanh(A.y), fast_tanh(A.z), fast_tanh(A.w)};
            f32x4 rB = {fast_tanh(B.x), fast_tanh(B.y), fast_tanh(B.z), fast_tanh(B.w)};
            *reinterpret_cast<f32x4*>(o_ptr + base0 + (size_t)o * NPIX) = rA;
            *reinterpret_cast<f32x4*>(o_ptr + base1 + (size_t)o * NPIX) = rB;
        }
    }

    // Per-channel partial sums keyed by tj (64-col group) for lighting pooling.
    // This thread's 8 px all lie in tj = cidx>>4; 16 consecutive lanes share tj.
    float s[6];
#pragma unroll
    for (int c = 0; c < 6; ++c)
        s[c] = (fa[c].x + fa[c].y + fa[c].z + fa[c].w) +
               (fb[c].x + fb[c].y + fb[c].z + fb[c].w);

    // segmented 16-lane butterfly allreduce (stays within each 16-lane group)
#pragma unroll
    for (int off = 1; off <= 8; off <<= 1) {
#pragma unroll
        for (int c = 0; c < 6; ++c) s[c] += __shfl_xor(s[c], off, 64);
    }

    // waves 0,2 cover tj 0..3; waves 1,3 cover tj 4..7
    __shared__ float red[4][4][8];
    int wave = t >> 6;
    int lane = t & 63;
    int g = lane >> 4;          // 16-lane group id within wave
    if ((lane & 15) == 0) {
#pragma unroll
        for (int c = 0; c < 6; ++c) red[wave][g][c] = s[c];
    }
    __syncthreads();
    if (t < 64) {
        int tj = t >> 3;        // 0..7
        int c = t & 7;          // 0..7 (6,7 = zero padding)
        float v = 0.f;
        if (c < 6)
            v = red[tj >> 2][tj & 3][c] + red[(tj >> 2) + 2][tj & 3][c];
        P[(((size_t)(n * NBAND + band)) * 8 + tj) * 8 + c] = v;
    }
}

// lighting: pooled mean over 128x128 patch = sum of 32 bands x 2 tj entries / 16384
__global__ __launch_bounds__(256) void lighting_kernel(
    const float* __restrict__ P, const float* __restrict__ Wl,
    const float* __restrict__ bl, float* __restrict__ out) {
    int tid = blockIdx.x * blockDim.x + threadIdx.x;
    if (tid > N_LIGHT) return;
    if (tid == N_LIGHT) {
        out[OFF_LOSS] = 0.0f;  // overlap_loss is identically zero
        return;
    }
    int n = tid / (27 * 49);
    int r = tid % (27 * 49);
    int o = r / 49;
    int r2 = r % 49;
    int i = r2 / 7;
    int j = r2 % 7;

    f32x4 s0 = {0.f, 0.f, 0.f, 0.f};   // channels 0..3
    float s4 = 0.f, s5 = 0.f;          // channels 4..5
    int band0 = i * 16;                // patch rows i*64 .. i*64+127 = bands 16i..16i+31
#pragma unroll 4
    for (int b = 0; b < 32; ++b) {
        const float* p = P + (((size_t)(n * NBAND + band0 + b)) * 8 + j) * 8;
        f32x4 a0 = *reinterpret_cast<const f32x4*>(p);        // tj=j,   c0..3
        f32x4 a1 = *reinterpret_cast<const f32x4*>(p + 4);    // tj=j,   c4..7
        f32x4 b0 = *reinterpret_cast<const f32x4*>(p + 8);    // tj=j+1, c0..3
        f32x4 b1 = *reinterpret_cast<const f32x4*>(p + 12);   // tj=j+1, c4..7
        s0 += a0 + b0;
        s4 += a1.x + b1.x;
        s5 += a1.y + b1.y;
    }
    float acc = bl[o];
    const float inv = 1.0f / 16384.0f;
    acc = fmaf(Wl[o * 6 + 0], s0.x * inv, acc);
    acc = fmaf(Wl[o * 6 + 1], s0.y * inv, acc);
    acc = fmaf(Wl[o * 6 + 2], s0.z * inv, acc);
    acc = fmaf(Wl[o * 6 + 3], s0.w * inv, acc);
    acc = fmaf(Wl[o * 6 + 4], s4 * inv, acc);
    acc = fmaf(Wl[o * 6 + 5], s5 * inv, acc);
    out[OFF_LIGHT + tid] = acc;
}

extern "C" void kernel_launch(void* const* d_in, const int* in_sizes, int n_in,
                              void* d_out, int out_size, void* d_ws, size_t ws_size,
                              hipStream_t stream) {
    const float* inT = (const float*)d_in[0];
    const float* inN = (const float*)d_in[1];
    const float* Wa = (const float*)d_in[2];
    const float* ba = (const float*)d_in[3];
    const float* Wn = (const float*)d_in[4];
    const float* bn = (const float*)d_in[5];
    const float* Ws = (const float*)d_in[6];
    const float* bs = (const float*)d_in[7];
    const float* Wl = (const float*)d_in[8];
    const float* bl = (const float*)d_in[9];
    float* out = (float*)d_out;
    float* P = (float*)d_ws;

    fused_heads_kernel<<<NBLK, 256, 0, stream>>>(
        inT, inN, Wa, ba, Wn, bn, Ws, bs, out, P);

    lighting_kernel<<<(N_LIGHT + 1 + 255) / 256, 256, 0, stream>>>(P, Wl, bl, out);
}

// Round 12
// 28.352 us; speedup vs baseline: 1.2102x; 1.2102x over previous
//
#include <hip/hip_runtime.h>

// Problem constants
#define NBATCH 8
#define HH 512
#define WW 512
#define NPIX (HH * WW)                 // 262144
#define IMG_ELEMS (NBATCH * 3 * NPIX)  // 6291456 floats per stitched output
#define OFF_ALBEDO 0
#define OFF_NORMAL ((size_t)IMG_ELEMS)
#define OFF_SHADING ((size_t)(2 * IMG_ELEMS))
#define OFF_LIGHT ((size_t)(3 * IMG_ELEMS))
#define N_LIGHT (NBATCH * 27 * 49)     // 10584
#define OFF_LOSS (OFF_LIGHT + N_LIGHT)
#define NBLK (NBATCH * 8 * 8 * 2)      // 1024 blocks: one 32-row x 64-col half-tile each
// Partial-sum table: P[bid][c], c padded to 8 -> 1024*8 floats = 32 KB in d_ws.
// Every slot written every call by exactly one block -> no zeroing, no atomics.
//
// Final search summary (R0-R11):
//  - Algebraic: stitch==identity (separable weights sum to 1), overlap_loss==0.
//  - Block sweep: 2048->30.1us, 1024->28.4us (opt), 512->29.5us.
//  - Dense per-instruction addressing mandatory (R4 strided pairs: 1.75x write amp).
//  - nt stores: neutral. Full-width 1KB bursts (R11): -5.9us regression
//    (reduce overhead + lost square-tile write locality).
//  - Single-kernel fusion: R8 release fences flush L2 (3.3x regression);
//    R9 fence-free atomicExch still +2us (waiter occupancy). Falsified.
//  - Steady state: main ~25us on 126MB L2-level traffic (~5 TB/s mixed R+W,
//    vs 6.8 TB/s pure-write fill ceiling); FETCH ~33MB (L3 retains inputs).

typedef float f32x4 __attribute__((ext_vector_type(4)));

__device__ __forceinline__ float fast_tanh(float x) {
    // tanh(x) = 1 - 2/(exp(2x)+1); saturates correctly at +/-inf of exp
    float e = __expf(2.0f * x);
    return 1.0f - 2.0f / (e + 1.0f);
}

// One block = 256 threads = one 32-row x 64-col half of a 64x64 tile; 8 px/thread
// as TWO dense 4-px chunks at rows y and y+16 (every load/store instruction is
// 64 lanes x 16B contiguous = 1 KB dense).
// grid = N * 8(ti) * 8(tj) * 2(half) = 1024 blocks = 4096 waves, 16 waves/CU.
__global__ __launch_bounds__(256) void fused_heads_kernel(
    const float* __restrict__ inT, const float* __restrict__ inN,
    const float* __restrict__ Wa, const float* __restrict__ ba,
    const float* __restrict__ Wn, const float* __restrict__ bn,
    const float* __restrict__ Ws, const float* __restrict__ bs,
    float* __restrict__ out, float* __restrict__ P) {
    int bid = blockIdx.x;
    int n = bid >> 7;           // / 128
    int rem = bid & 127;
    int ti = rem >> 4;
    int rem2 = rem & 15;
    int tj = rem2 >> 1;
    int half = rem2 & 1;

    int t = threadIdx.x;
    int rowc = t >> 4;          // 0..15
    int col4 = t & 15;          // 0..15
    int y = ti * 64 + half * 32 + rowc;   // second chunk at y+16
    int x = tj * 64 + col4 * 4;

    // 12 independent fully-dense f32x4 loads (6 channels x 2 row-chunks)
    f32x4 fa[6], fb[6];
    size_t base0 = ((size_t)(n * 3) * HH + y) * WW + x;
    size_t base1 = base0 + (size_t)16 * WW;
#pragma unroll
    for (int c = 0; c < 3; ++c) {
        fa[c]     = *reinterpret_cast<const f32x4*>(inT + base0 + (size_t)c * NPIX);
        fb[c]     = *reinterpret_cast<const f32x4*>(inT + base1 + (size_t)c * NPIX);
        fa[c + 3] = *reinterpret_cast<const f32x4*>(inN + base0 + (size_t)c * NPIX);
        fb[c + 3] = *reinterpret_cast<const f32x4*>(inN + base1 + (size_t)c * NPIX);
    }

    // Three heads: out[n,o,y,x] = tanh(W[o,:].feat + b[o])
    // (stitch weights are separable and sum to 1 at every pixel -> stitch == identity;
    //  overlap_loss is identically zero since overlapping patches see the same pixels)
#pragma unroll
    for (int h = 0; h < 3; ++h) {
        const float* W = (h == 0) ? Wa : (h == 1) ? Wn : Ws;
        const float* b = (h == 0) ? ba : (h == 1) ? bn : bs;
        float* o_ptr = out + ((h == 0) ? OFF_ALBEDO : (h == 1) ? OFF_NORMAL : OFF_SHADING);
#pragma unroll
        for (int o = 0; o < 3; ++o) {
            float bv = b[o];
            f32x4 A = {bv, bv, bv, bv};
            f32x4 B = {bv, bv, bv, bv};
#pragma unroll
            for (int c = 0; c < 6; ++c) {
                float w = W[o * 6 + c];
                A.x = fmaf(w, fa[c].x, A.x);
                A.y = fmaf(w, fa[c].y, A.y);
                A.z = fmaf(w, fa[c].z, A.z);
                A.w = fmaf(w, fa[c].w, A.w);
                B.x = fmaf(w, fb[c].x, B.x);
                B.y = fmaf(w, fb[c].y, B.y);
                B.z = fmaf(w, fb[c].z, B.z);
                B.w = fmaf(w, fb[c].w, B.w);
            }
            f32x4 rA = {fast_tanh(A.x), fast_tanh(A.y), fast_tanh(A.z), fast_tanh(A.w)};
            f32x4 rB = {fast_tanh(B.x), fast_tanh(B.y), fast_tanh(B.z), fast_tanh(B.w)};
            *reinterpret_cast<f32x4*>(o_ptr + base0 + (size_t)o * NPIX) = rA;
            *reinterpret_cast<f32x4*>(o_ptr + base1 + (size_t)o * NPIX) = rB;
        }
    }

    // Per-channel partial sums of this block's 32x64 half-tile (for lighting pooling)
    float s[6];
#pragma unroll
    for (int c = 0; c < 6; ++c)
        s[c] = (fa[c].x + fa[c].y + fa[c].z + fa[c].w) +
               (fb[c].x + fb[c].y + fb[c].z + fb[c].w);

    // wave (64-lane) butterfly reduce
#pragma unroll
    for (int off = 32; off > 0; off >>= 1) {
#pragma unroll
        for (int c = 0; c < 6; ++c) s[c] += __shfl_down(s[c], off, 64);
    }

    __shared__ float red[4][6];
    int wave = t >> 6;
    int lane = t & 63;
    if (lane == 0) {
#pragma unroll
        for (int c = 0; c < 6; ++c) red[wave][c] = s[c];
    }
    __syncthreads();
    if (t < 6) {
        float v = red[0][t] + red[1][t] + red[2][t] + red[3][t];
        P[(size_t)bid * 8 + t] = v;   // deterministic slot, no atomics, no memset
    }
}

// lighting: pooled mean over each 128x128 patch = sum of 8 half-tile partials / 16384
__global__ __launch_bounds__(256) void lighting_kernel(
    const float* __restrict__ P, const float* __restrict__ Wl,
    const float* __restrict__ bl, float* __restrict__ out) {
    int tid = blockIdx.x * blockDim.x + threadIdx.x;
    if (tid > N_LIGHT) return;
    if (tid == N_LIGHT) {
        out[OFF_LOSS] = 0.0f;  // overlap_loss is identically zero
        return;
    }
    int n = tid / (27 * 49);
    int r = tid % (27 * 49);
    int o = r / 49;
    int r2 = r % 49;
    int i = r2 / 7;
    int j = r2 % 7;

    f32x4 s0 = {0.f, 0.f, 0.f, 0.f};   // channels 0..3
    float s4 = 0.f, s5 = 0.f;          // channels 4..5
#pragma unroll
    for (int di = 0; di < 2; ++di) {
#pragma unroll
        for (int dj = 0; dj < 2; ++dj) {
            int ti = i + di;
            int tj = j + dj;
#pragma unroll
            for (int hf = 0; hf < 2; ++hf) {
                int b = ((n * 8 + ti) * 8 + tj) * 2 + hf;
                const float* p = P + (size_t)b * 8;
                f32x4 v0 = *reinterpret_cast<const f32x4*>(p);
                f32x4 v1 = *reinterpret_cast<const f32x4*>(p + 4);
                s0 += v0;
                s4 += v1.x;
                s5 += v1.y;
            }
        }
    }
    float acc = bl[o];
    const float inv = 1.0f / 16384.0f;
    acc = fmaf(Wl[o * 6 + 0], s0.x * inv, acc);
    acc = fmaf(Wl[o * 6 + 1], s0.y * inv, acc);
    acc = fmaf(Wl[o * 6 + 2], s0.z * inv, acc);
    acc = fmaf(Wl[o * 6 + 3], s0.w * inv, acc);
    acc = fmaf(Wl[o * 6 + 4], s4 * inv, acc);
    acc = fmaf(Wl[o * 6 + 5], s5 * inv, acc);
    out[OFF_LIGHT + tid] = acc;
}

extern "C" void kernel_launch(void* const* d_in, const int* in_sizes, int n_in,
                              void* d_out, int out_size, void* d_ws, size_t ws_size,
                              hipStream_t stream) {
    const float* inT = (const float*)d_in[0];
    const float* inN = (const float*)d_in[1];
    const float* Wa = (const float*)d_in[2];
    const float* ba = (const float*)d_in[3];
    const float* Wn = (const float*)d_in[4];
    const float* bn = (const float*)d_in[5];
    const float* Ws = (const float*)d_in[6];
    const float* bs = (const float*)d_in[7];
    const float* Wl = (const float*)d_in[8];
    const float* bl = (const float*)d_in[9];
    float* out = (float*)d_out;
    float* P = (float*)d_ws;

    fused_heads_kernel<<<NBLK, 256, 0, stream>>>(
        inT, inN, Wa, ba, Wn, bn, Ws, bs, out, P);

    lighting_kernel<<<(N_LIGHT + 1 + 255) / 256, 256, 0, stream>>>(P, Wl, bl, out);
}